// Round 15
// baseline (106.125 us; speedup 1.0000x reference)
//
#include <hip/hip_runtime.h>
#include <hip/hip_bf16.h>

typedef __bf16 bf16x8 __attribute__((ext_vector_type(8)));
typedef float  f32x4  __attribute__((ext_vector_type(4)));

#define Bsz 64
#define Tdim 2048
#define Edim 512
#define Ddim 1024
#define Udim 128
#define CHUNK 256
#define NCHUNK 8           // Tdim / CHUNK

__device__ inline bf16x8 cvt8(float4 a, float4 b) {   // -> v_cvt_pk_bf16_f32 x4
    bf16x8 h;
    h[0] = (__bf16)a.x; h[1] = (__bf16)a.y; h[2] = (__bf16)a.z; h[3] = (__bf16)a.w;
    h[4] = (__bf16)b.x; h[5] = (__bf16)b.y; h[6] = (__bf16)b.z; h[7] = (__bf16)b.w;
    return h;
}

__device__ inline float fast_tanh(float x) {
    float e = __expf(2.f * x);
    return 1.f - __fdividef(2.f, e + 1.f);
}

// ---- K_prep: blocks [0,256): qb (8 jobs/wave); [256,272): Wk -> FRAGMENT-MAJOR bf16 ----
// wkbf entry E in [0,8192), 8 bf16 each: E = (ks*8 + n)*64 + l
//   u = n*16 + (l&15); e = ks*32 + (l>>4)*8   (ks = K-step 0..15)
__global__ __launch_bounds__(256) void k_prep(const float* __restrict__ q,
                                              const float* __restrict__ Wq,
                                              const float* __restrict__ bparam,
                                              const float* __restrict__ convb,
                                              const float* __restrict__ Wk,
                                              unsigned short* __restrict__ wkbf,
                                              float* __restrict__ qb) {
    int bid = blockIdx.x, tid = threadIdx.x;
    if (bid >= 256) {
        int cb = bid - 256;
        #pragma unroll
        for (int k = 0; k < 2; ++k) {
            int E = (cb * 256 + tid) * 2 + k;          // [0, 8192)
            int l  = E & 63;
            int n  = (E >> 6) & 7;
            int ks = E >> 9;
            int u  = n * 16 + (l & 15);
            int e  = ks * 32 + (l >> 4) * 8;
            const float* src = Wk + (size_t)u * Edim + e;
            float4 a = *reinterpret_cast<const float4*>(src);
            float4 b = *reinterpret_cast<const float4*>(src + 4);
            *reinterpret_cast<bf16x8*>(wkbf + (size_t)E * 8) = cvt8(a, b);
        }
        return;
    }
    int wg   = bid * 4 + (tid >> 6);
    int lane = tid & 63;
    int b  = wg >> 4;
    int u0 = (wg & 15) * 8;
    const float* qr = q + (size_t)b * Ddim + lane * 16;
    float4 qv[4];
    #pragma unroll
    for (int i = 0; i < 4; ++i) qv[i] = *reinterpret_cast<const float4*>(qr + i * 4);
    float s[8];
    #pragma unroll
    for (int jj = 0; jj < 8; ++jj) {
        const float* wr = Wq + (size_t)(u0 + jj) * Ddim + lane * 16;
        float acc = 0.f;
        #pragma unroll
        for (int i = 0; i < 4; ++i) {
            float4 w = *reinterpret_cast<const float4*>(wr + i * 4);
            acc += qv[i].x * w.x + qv[i].y * w.y + qv[i].z * w.z + qv[i].w * w.w;
        }
        s[jj] = acc;
    }
    #pragma unroll
    for (int m = 32; m; m >>= 1) {
        #pragma unroll
        for (int jj = 0; jj < 8; ++jj) s[jj] += __shfl_xor(s[jj], m);
    }
    if (lane == 0) {
        #pragma unroll
        for (int jj = 0; jj < 8; ++jj)
            qb[b * 128 + u0 + jj] = s[jj] + bparam[u0 + jj] + convb[u0 + jj];
    }
}

// ---- K1: 512 thr (8 waves), 256 t x 128 u; ZERO-BARRIER GEMM, wave-private operands ----
// Each wave owns 32 rows x all 128 u. A-fragments loaded per-lane from global (f32 -> cvt),
// B-fragments from fragment-major wkbf (L2-resident, lane-coalesced). No LDS in the K-loop.
__global__ __launch_bounds__(512, 3) void k_score_ctx(const float* __restrict__ enc,
                                                      const float* __restrict__ prev,
                                                      const unsigned short* __restrict__ wkbf,
                                                      const float* __restrict__ qb,
                                                      const float* __restrict__ conv_w,
                                                      const float* __restrict__ v_w,
                                                      const float* __restrict__ v_b,
                                                      const int* __restrict__ lengths,
                                                      float* __restrict__ score_out,
                                                      float* __restrict__ m_ws,
                                                      float* __restrict__ l_ws,
                                                      float* __restrict__ c_ws) {
    __shared__ float s_prev[258];
    __shared__ float s_qb[128];
    __shared__ float s_vw[128];
    __shared__ float s_cw[3][128];
    __shared__ float s_score[256];
    __shared__ float s_p[256];
    __shared__ float s_redm[4], s_redl[4];
    __shared__ alignas(16) float s_cred[3][128][4];

    const int tid   = threadIdx.x;
    const int b     = blockIdx.x;               // actives front-loaded
    const int chunk = blockIdx.y;
    const int t0    = chunk * CHUNK;
    const int lane  = tid & 63, wid = tid >> 6;
    const int len   = lengths[b];
    const int pidx  = b * NCHUNK + chunk;

    if (t0 >= len) {
        if (tid == 0) { m_ws[pidx] = -3.4e38f; l_ws[pidx] = 0.f; }
        return;
    }

    if (tid < 128) {
        s_qb[tid]    = qb[b * 128 + tid];
        s_vw[tid]    = v_w[tid];
        s_cw[0][tid] = conv_w[tid * 3 + 0];
        s_cw[1][tid] = conv_w[tid * 3 + 1];
        s_cw[2][tid] = conv_w[tid * 3 + 2];
    }
    if (tid >= 128 && tid < 128 + 258) {
        int k = tid - 128;
        int idx = t0 - 1 + k;
        s_prev[k] = (idx >= 0 && idx < Tdim) ? prev[b * Tdim + idx] : 0.f;
    }

    const float* encb = enc + ((size_t)b * Tdim + t0) * Edim;

    // wave-private A row pointers: row = wid*32 + m*16 + (lane&15), e-base = (lane>>4)*8
    const float* rowp[2];
    #pragma unroll
    for (int m = 0; m < 2; ++m)
        rowp[m] = encb + (size_t)(wid * 32 + m * 16 + (lane & 15)) * Edim + (lane >> 4) * 8;
    const unsigned short* wb = wkbf + lane * 8;

    f32x4 acc[2][8];
    #pragma unroll
    for (int m = 0; m < 2; ++m)
        #pragma unroll
        for (int n = 0; n < 8; ++n) acc[m][n] = (f32x4){0.f, 0.f, 0.f, 0.f};

    // ---- zero-barrier GEMM: 16 K-steps fully unrolled; loads pipeline under MFMA ----
    #pragma unroll
    for (int ks = 0; ks < 16; ++ks) {
        bf16x8 af[2];
        #pragma unroll
        for (int m = 0; m < 2; ++m) {
            float4 a0 = *reinterpret_cast<const float4*>(rowp[m] + ks * 32);
            float4 a1 = *reinterpret_cast<const float4*>(rowp[m] + ks * 32 + 4);
            af[m] = cvt8(a0, a1);
        }
        #pragma unroll
        for (int n = 0; n < 8; ++n) {
            bf16x8 bv = *reinterpret_cast<const bf16x8*>(wb + (size_t)(ks * 8 + n) * 512);
            acc[0][n] = __builtin_amdgcn_mfma_f32_16x16x32_bf16(af[0], bv, acc[0][n], 0, 0, 0);
            acc[1][n] = __builtin_amdgcn_mfma_f32_16x16x32_bf16(af[1], bv, acc[1][n], 0, 0, 0);
        }
    }

    __syncthreads();   // s_qb / s_prev ready for epilogue

    // epilogue: wave-exclusive rows — score = v·tanh(acc + qb + conv) + v_b
    float sc[2][4] = {{0.f,0.f,0.f,0.f},{0.f,0.f,0.f,0.f}};
    #pragma unroll
    for (int m = 0; m < 2; ++m) {
        #pragma unroll
        for (int n = 0; n < 8; ++n) {
            int u = n * 16 + (lane & 15);
            float c0 = s_cw[0][u], c1 = s_cw[1][u], c2 = s_cw[2][u];
            float qbu = s_qb[u], vwu = s_vw[u];
            #pragma unroll
            for (int j = 0; j < 4; ++j) {
                int r = wid * 32 + m * 16 + (lane >> 4) * 4 + j;
                float conv = s_prev[r] * c0 + s_prev[r + 1] * c1 + s_prev[r + 2] * c2;
                sc[m][j] += vwu * fast_tanh(acc[m][n][j] + qbu + conv);
            }
        }
    }
    #pragma unroll
    for (int m = 0; m < 2; ++m)
        #pragma unroll
        for (int j = 0; j < 4; ++j) {
            sc[m][j] += __shfl_xor(sc[m][j], 1);
            sc[m][j] += __shfl_xor(sc[m][j], 2);
            sc[m][j] += __shfl_xor(sc[m][j], 4);
            sc[m][j] += __shfl_xor(sc[m][j], 8);
        }
    if ((lane & 15) == 0) {
        float vb = v_b[0];
        #pragma unroll
        for (int m = 0; m < 2; ++m) {
            int r = wid * 32 + m * 16 + (lane >> 4) * 4;
            #pragma unroll
            for (int j = 0; j < 4; ++j) {
                float s = sc[m][j] + vb;
                s_score[r + j] = s;
                score_out[b * Tdim + t0 + r + j] = s;   // raw; normalized by combine
            }
        }
    }
    __syncthreads();

    // block softmax over 256 rows
    float sv = 0.f;
    if (tid < 256) sv = (t0 + tid < len) ? s_score[tid] : -3.4e38f;
    {
        float m = (tid < 256) ? sv : -3.4e38f;
        #pragma unroll
        for (int s = 32; s; s >>= 1) m = fmaxf(m, __shfl_xor(m, s));
        if (tid < 256 && lane == 0) s_redm[wid] = m;
    }
    __syncthreads();
    float M = fmaxf(fmaxf(s_redm[0], s_redm[1]), fmaxf(s_redm[2], s_redm[3]));
    float p = 0.f;
    if (tid < 256) {
        p = (t0 + tid < len) ? __expf(sv - M) : 0.f;
        s_p[tid] = p;
    }
    {
        float l = (tid < 256) ? p : 0.f;
        #pragma unroll
        for (int s = 32; s; s >>= 1) l += __shfl_xor(l, s);
        if (tid < 256 && lane == 0) s_redl[wid] = l;
    }
    __syncthreads();
    if (tid == 0) {
        m_ws[pidx] = M;
        l_ws[pidx] = s_redl[0] + s_redl[1] + s_redl[2] + s_redl[3];
    }

    // partial context: c[e] = sum_t p_t * enc[t,e]  (f32 tile re-read; L2/L3-hot)
    {
        int e4 = (tid & 127) * 4;
        int tg = tid >> 7;                       // 4 t-groups
        float4 a = make_float4(0.f, 0.f, 0.f, 0.f);
        #pragma unroll 4
        for (int t = tg; t < CHUNK; t += 4) {
            float pt = s_p[t];
            float4 v = *reinterpret_cast<const float4*>(encb + (size_t)t * Edim + e4);
            a.x += pt * v.x; a.y += pt * v.y; a.z += pt * v.z; a.w += pt * v.w;
        }
        if (tg > 0) *reinterpret_cast<float4*>(&s_cred[tg - 1][tid & 127][0]) = a;
        __syncthreads();
        if (tg == 0) {
            #pragma unroll
            for (int g = 0; g < 3; ++g) {
                float4 o = *reinterpret_cast<const float4*>(&s_cred[g][tid][0]);
                a.x += o.x; a.y += o.y; a.z += o.z; a.w += o.w;
            }
            *reinterpret_cast<float4*>(c_ws + (size_t)pidx * Edim + e4) = a;
        }
    }
}

// ---- K2: combine partials -> context + normalized attn ----
__global__ __launch_bounds__(256) void k_combine(const float* __restrict__ m_ws,
                                                 const float* __restrict__ l_ws,
                                                 const float* __restrict__ c_ws,
                                                 const int* __restrict__ lengths,
                                                 float* __restrict__ ctx,
                                                 float* __restrict__ attn) {
    int b = blockIdx.x, tid = threadIdx.x;
    int lane = tid & 63, wid = tid >> 6;
    __shared__ float s_w[NCHUNK];
    __shared__ float sM, sinvL;

    if (wid == 0) {
        float mj = (lane < NCHUNK) ? m_ws[b * NCHUNK + lane] : -3.4e38f;
        float lj = (lane < NCHUNK) ? l_ws[b * NCHUNK + lane] : 0.f;
        float M = mj;
        #pragma unroll
        for (int s = 32; s; s >>= 1) M = fmaxf(M, __shfl_xor(M, s));
        float w = (lj > 0.f) ? __expf(mj - M) : 0.f;
        float L = lj * w;
        #pragma unroll
        for (int s = 32; s; s >>= 1) L += __shfl_xor(L, s);
        if (lane < NCHUNK) s_w[lane] = w;
        if (lane == 0) { sM = M; sinvL = 1.f / L; }
    }
    __syncthreads();
    float M = sM, invL = sinvL;

    {
        int e2 = tid * 2;
        float ax = 0.f, ay = 0.f;
        #pragma unroll
        for (int j = 0; j < NCHUNK; ++j) {
            float w = s_w[j];
            if (w != 0.f) {
                float2 v = *reinterpret_cast<const float2*>(c_ws + ((size_t)(b * NCHUNK + j)) * Edim + e2);
                ax += w * v.x; ay += w * v.y;
            }
        }
        *reinterpret_cast<float2*>(ctx + (size_t)b * Edim + e2) = make_float2(ax * invL, ay * invL);
    }

    int len = lengths[b];
    #pragma unroll
    for (int i = 0; i < Tdim / 256; ++i) {
        int t = tid + i * 256;
        float s = attn[(size_t)b * Tdim + t];
        attn[(size_t)b * Tdim + t] = (t < len) ? __expf(s - M) * invL : 0.f;
    }
}

extern "C" void kernel_launch(void* const* d_in, const int* in_sizes, int n_in,
                              void* d_out, int out_size, void* d_ws, size_t ws_size,
                              hipStream_t stream) {
    const float* queries = (const float*)d_in[0];
    const float* prev    = (const float*)d_in[1];
    const float* enc     = (const float*)d_in[2];
    const float* conv_w  = (const float*)d_in[3];
    const float* conv_b  = (const float*)d_in[4];
    const float* Wq      = (const float*)d_in[5];
    const float* Wk      = (const float*)d_in[6];
    const float* v_w     = (const float*)d_in[7];
    const float* v_b     = (const float*)d_in[8];
    const float* bparam  = (const float*)d_in[9];
    const int*   lengths = (const int*)d_in[10];

    float* out  = (float*)d_out;
    float* ctx  = out;                       // B*E = 32768
    float* attn = out + Bsz * Edim;          // B*T = 131072

    char* ws = (char*)d_ws;
    unsigned short* wkbf = (unsigned short*)ws;                 // 128 KB (fragment-major)
    float* qb   = (float*)(ws + 131072);                        // 32 KB
    float* m_ws = (float*)(ws + 163840);                        // 2 KB
    float* l_ws = (float*)(ws + 172032);                        // 2 KB
    float* c_ws = (float*)(ws + 196608);                        // 1 MB

    k_prep<<<272, 256, 0, stream>>>(queries, Wq, bparam, conv_b, Wk, wkbf, qb);
    k_score_ctx<<<dim3(Bsz, NCHUNK), 512, 0, stream>>>(enc, prev, wkbf, qb, conv_w, v_w, v_b,
                                                       lengths, attn, m_ws, l_ws, c_ws);
    k_combine<<<Bsz, 256, 0, stream>>>(m_ws, l_ws, c_ws, lengths, ctx, attn);
}

// Round 16
// 77.057 us; speedup vs baseline: 1.3772x; 1.3772x over previous
//
#include <hip/hip_runtime.h>
#include <hip/hip_bf16.h>

typedef __bf16 bf16x8 __attribute__((ext_vector_type(8)));
typedef float  f32x4  __attribute__((ext_vector_type(4)));

#define Bsz 64
#define Tdim 2048
#define Edim 512
#define Ddim 1024
#define Udim 128
#define CHUNK 256
#define NCHUNK 8           // Tdim / CHUNK

__device__ inline bf16x8 cvt8(float4 a, float4 b) {   // -> v_cvt_pk_bf16_f32 x4
    bf16x8 h;
    h[0] = (__bf16)a.x; h[1] = (__bf16)a.y; h[2] = (__bf16)a.z; h[3] = (__bf16)a.w;
    h[4] = (__bf16)b.x; h[5] = (__bf16)b.y; h[6] = (__bf16)b.z; h[7] = (__bf16)b.w;
    return h;
}

__device__ inline float fast_tanh(float x) {
    float e = __expf(2.f * x);
    return 1.f - __fdividef(2.f, e + 1.f);
}

// ---- K_prep: blocks [0,256): qb (8 jobs/wave); [256,272): Wk -> PRE-SWIZZLED bf16 ----
// wkbf: 8 es-slices of 16384 B; element (u,c8) at byte ((u*128+c8*16)^((u&7)<<4)) in slice.
__global__ __launch_bounds__(256) void k_prep(const float* __restrict__ q,
                                              const float* __restrict__ Wq,
                                              const float* __restrict__ bparam,
                                              const float* __restrict__ convb,
                                              const float* __restrict__ Wk,
                                              unsigned short* __restrict__ wkbf,
                                              float* __restrict__ qb) {
    int bid = blockIdx.x, tid = threadIdx.x;
    if (bid >= 256) {
        int cb = bid - 256;
        #pragma unroll
        for (int k = 0; k < 2; ++k) {
            int E = (cb * 256 + tid) * 2 + k;          // [0, 8192)
            int c8 = E & 7;
            int u  = (E >> 3) & 127;
            int es = E >> 10;
            const float* src = Wk + (size_t)u * Edim + es * 64 + c8 * 8;
            float4 a = *reinterpret_cast<const float4*>(src);
            float4 b = *reinterpret_cast<const float4*>(src + 4);
            int dst = es * 16384 + ((u * 128 + c8 * 16) ^ ((u & 7) << 4));
            *reinterpret_cast<bf16x8*>(reinterpret_cast<char*>(wkbf) + dst) = cvt8(a, b);
        }
        return;
    }
    int wg   = bid * 4 + (tid >> 6);
    int lane = tid & 63;
    int b  = wg >> 4;
    int u0 = (wg & 15) * 8;
    const float* qr = q + (size_t)b * Ddim + lane * 16;
    float4 qv[4];
    #pragma unroll
    for (int i = 0; i < 4; ++i) qv[i] = *reinterpret_cast<const float4*>(qr + i * 4);
    float s[8];
    #pragma unroll
    for (int jj = 0; jj < 8; ++jj) {
        const float* wr = Wq + (size_t)(u0 + jj) * Ddim + lane * 16;
        float acc = 0.f;
        #pragma unroll
        for (int i = 0; i < 4; ++i) {
            float4 w = *reinterpret_cast<const float4*>(wr + i * 4);
            acc += qv[i].x * w.x + qv[i].y * w.y + qv[i].z * w.z + qv[i].w * w.w;
        }
        s[jj] = acc;
    }
    #pragma unroll
    for (int m = 32; m; m >>= 1) {
        #pragma unroll
        for (int jj = 0; jj < 8; ++jj) s[jj] += __shfl_xor(s[jj], m);
    }
    if (lane == 0) {
        #pragma unroll
        for (int jj = 0; jj < 8; ++jj)
            qb[b * 128 + u0 + jj] = s[jj] + bparam[u0 + jj] + convb[u0 + jj];
    }
}

// ---- K1: 512 threads (8 waves), tile 256 t x 128 u; each wave owns 32 rows x all u ----
__global__ __launch_bounds__(512, 4) void k_score_ctx(const float* __restrict__ enc,
                                                      const float* __restrict__ prev,
                                                      const unsigned short* __restrict__ wkbf,
                                                      const float* __restrict__ qb,
                                                      const float* __restrict__ conv_w,
                                                      const float* __restrict__ v_w,
                                                      const float* __restrict__ v_b,
                                                      const int* __restrict__ lengths,
                                                      float* __restrict__ score_out,
                                                      float* __restrict__ m_ws,
                                                      float* __restrict__ l_ws,
                                                      float* __restrict__ c_ws) {
    __shared__ alignas(16) unsigned short At[256 * 64];     // 32 KB, swizzled
    __shared__ alignas(16) unsigned short Bt[128 * 64];     // 16 KB, swizzled (preswz global)
    __shared__ float s_prev[258];
    __shared__ float s_qb[128];
    __shared__ float s_vw[128];
    __shared__ float s_cw[3][128];
    __shared__ float s_score[256];
    __shared__ float s_p[256];
    __shared__ float s_redm[4], s_redl[4];
    __shared__ alignas(16) float s_cred[3][128][4];         // 6 KB

    const int tid   = threadIdx.x;
    const int b     = blockIdx.x;               // actives front-loaded
    const int chunk = blockIdx.y;
    const int t0    = chunk * CHUNK;
    const int lane  = tid & 63, wid = tid >> 6;
    const int len   = lengths[b];
    const int pidx  = b * NCHUNK + chunk;

    if (t0 >= len) {
        if (tid == 0) { m_ws[pidx] = -3.4e38f; l_ws[pidx] = 0.f; }
        return;
    }

    if (tid < 128) {
        s_qb[tid]    = qb[b * 128 + tid];
        s_vw[tid]    = v_w[tid];
        s_cw[0][tid] = conv_w[tid * 3 + 0];
        s_cw[1][tid] = conv_w[tid * 3 + 1];
        s_cw[2][tid] = conv_w[tid * 3 + 2];
    }
    if (tid >= 128 && tid < 128 + 258) {
        int k = tid - 128;
        int idx = t0 - 1 + k;
        s_prev[k] = (idx >= 0 && idx < Tdim) ? prev[b * Tdim + idx] : 0.f;
    }

    const float* encb = enc + ((size_t)b * Tdim + t0) * Edim;

    f32x4 acc[2][8];
    #pragma unroll
    for (int m = 0; m < 2; ++m)
        #pragma unroll
        for (int n = 0; n < 8; ++n) acc[m][n] = (f32x4){0.f, 0.f, 0.f, 0.f};

    for (int es = 0; es < 8; ++es) {
        const int e0 = es * 64;
        // stage B: async global->LDS, 16B/lane x2, linear (source pre-swizzled)
        {
            const char* wsrc = reinterpret_cast<const char*>(wkbf) + es * 16384 + tid * 16;
            char* bdst = reinterpret_cast<char*>(Bt) + tid * 16;
            __builtin_amdgcn_global_load_lds(
                (const __attribute__((address_space(1))) unsigned int*)(wsrc),
                (__attribute__((address_space(3))) unsigned int*)(bdst), 16, 0, 0);
            __builtin_amdgcn_global_load_lds(
                (const __attribute__((address_space(1))) unsigned int*)(wsrc + 8192),
                (__attribute__((address_space(3))) unsigned int*)(bdst + 8192), 16, 0, 0);
        }
        // stage A: 2048 slots of 16B; thread handles lin = tid + i*512, two passes of 2 slots
        #pragma unroll
        for (int pass = 0; pass < 2; ++pass) {
            float4 ra[4];
            int lin0 = tid + pass * 1024;
            #pragma unroll
            for (int sl = 0; sl < 2; ++sl) {
                int lin = lin0 + sl * 512;
                int r = lin >> 3, c8 = lin & 7;
                const float* src = encb + (size_t)r * Edim + e0 + c8 * 8;
                ra[2 * sl]     = *reinterpret_cast<const float4*>(src);
                ra[2 * sl + 1] = *reinterpret_cast<const float4*>(src + 4);
            }
            #pragma unroll
            for (int sl = 0; sl < 2; ++sl) {
                int lin = lin0 + sl * 512;
                int r = lin >> 3, c8 = lin & 7;
                int off = (r * 128 + c8 * 16) ^ ((r & 7) << 4);
                *reinterpret_cast<bf16x8*>(reinterpret_cast<char*>(At) + off) =
                    cvt8(ra[2 * sl], ra[2 * sl + 1]);
            }
        }
        __syncthreads();
        #pragma unroll
        for (int kk = 0; kk < 2; ++kk) {
            bf16x8 af[2];
            #pragma unroll
            for (int m = 0; m < 2; ++m) {
                int ar = wid * 32 + m * 16 + (lane & 15);
                int abyte = (ar * 128 + kk * 64 + (lane >> 4) * 16) ^ ((ar & 7) << 4);
                af[m] = *reinterpret_cast<const bf16x8*>(reinterpret_cast<const char*>(At) + abyte);
            }
            #pragma unroll
            for (int n = 0; n < 8; ++n) {
                int br = n * 16 + (lane & 15);
                int bbyte = (br * 128 + kk * 64 + (lane >> 4) * 16) ^ ((br & 7) << 4);
                bf16x8 bv = *reinterpret_cast<const bf16x8*>(reinterpret_cast<const char*>(Bt) + bbyte);
                acc[0][n] = __builtin_amdgcn_mfma_f32_16x16x32_bf16(af[0], bv, acc[0][n], 0, 0, 0);
                acc[1][n] = __builtin_amdgcn_mfma_f32_16x16x32_bf16(af[1], bv, acc[1][n], 0, 0, 0);
            }
        }
        __syncthreads();
    }

    // epilogue: wave-exclusive rows — score = v·tanh(acc + qb + conv) + v_b
    float sc[2][4] = {{0.f,0.f,0.f,0.f},{0.f,0.f,0.f,0.f}};
    #pragma unroll
    for (int m = 0; m < 2; ++m) {
        #pragma unroll
        for (int n = 0; n < 8; ++n) {
            int u = n * 16 + (lane & 15);
            float c0 = s_cw[0][u], c1 = s_cw[1][u], c2 = s_cw[2][u];
            float qbu = s_qb[u], vwu = s_vw[u];
            #pragma unroll
            for (int j = 0; j < 4; ++j) {
                int r = wid * 32 + m * 16 + (lane >> 4) * 4 + j;
                float conv = s_prev[r] * c0 + s_prev[r + 1] * c1 + s_prev[r + 2] * c2;
                sc[m][j] += vwu * fast_tanh(acc[m][n][j] + qbu + conv);
            }
        }
    }
    #pragma unroll
    for (int m = 0; m < 2; ++m)
        #pragma unroll
        for (int j = 0; j < 4; ++j) {
            sc[m][j] += __shfl_xor(sc[m][j], 1);
            sc[m][j] += __shfl_xor(sc[m][j], 2);
            sc[m][j] += __shfl_xor(sc[m][j], 4);
            sc[m][j] += __shfl_xor(sc[m][j], 8);
        }
    if ((lane & 15) == 0) {
        float vb = v_b[0];
        #pragma unroll
        for (int m = 0; m < 2; ++m) {
            int r = wid * 32 + m * 16 + (lane >> 4) * 4;
            #pragma unroll
            for (int j = 0; j < 4; ++j) {
                float s = sc[m][j] + vb;
                s_score[r + j] = s;
                score_out[b * Tdim + t0 + r + j] = s;   // raw; normalized by combine
            }
        }
    }
    __syncthreads();

    // block softmax over 256 rows (waves 0-3 cover rows = tid)
    float sv = 0.f;
    if (tid < 256) sv = (t0 + tid < len) ? s_score[tid] : -3.4e38f;
    {
        float m = (tid < 256) ? sv : -3.4e38f;
        #pragma unroll
        for (int s = 32; s; s >>= 1) m = fmaxf(m, __shfl_xor(m, s));
        if (tid < 256 && lane == 0) s_redm[wid] = m;
    }
    __syncthreads();
    float M = fmaxf(fmaxf(s_redm[0], s_redm[1]), fmaxf(s_redm[2], s_redm[3]));
    float p = 0.f;
    if (tid < 256) {
        p = (t0 + tid < len) ? __expf(sv - M) : 0.f;
        s_p[tid] = p;
    }
    {
        float l = (tid < 256) ? p : 0.f;
        #pragma unroll
        for (int s = 32; s; s >>= 1) l += __shfl_xor(l, s);
        if (tid < 256 && lane == 0) s_redl[wid] = l;
    }
    __syncthreads();
    if (tid == 0) {
        m_ws[pidx] = M;
        l_ws[pidx] = s_redl[0] + s_redl[1] + s_redl[2] + s_redl[3];
    }

    // partial context: c[e] = sum_t p_t * enc[t,e]  (f32 tile re-read; L2/L3-hot)
    {
        int e4 = (tid & 127) * 4;
        int tg = tid >> 7;                       // 4 t-groups
        float4 a = make_float4(0.f, 0.f, 0.f, 0.f);
        #pragma unroll 4
        for (int t = tg; t < CHUNK; t += 4) {
            float pt = s_p[t];
            float4 v = *reinterpret_cast<const float4*>(encb + (size_t)t * Edim + e4);
            a.x += pt * v.x; a.y += pt * v.y; a.z += pt * v.z; a.w += pt * v.w;
        }
        if (tg > 0) *reinterpret_cast<float4*>(&s_cred[tg - 1][tid & 127][0]) = a;
        __syncthreads();
        if (tg == 0) {
            #pragma unroll
            for (int g = 0; g < 3; ++g) {
                float4 o = *reinterpret_cast<const float4*>(&s_cred[g][tid][0]);
                a.x += o.x; a.y += o.y; a.z += o.z; a.w += o.w;
            }
            *reinterpret_cast<float4*>(c_ws + (size_t)pidx * Edim + e4) = a;
        }
    }
}

// ---- K2: combine partials -> context + normalized attn ----
__global__ __launch_bounds__(256) void k_combine(const float* __restrict__ m_ws,
                                                 const float* __restrict__ l_ws,
                                                 const float* __restrict__ c_ws,
                                                 const int* __restrict__ lengths,
                                                 float* __restrict__ ctx,
                                                 float* __restrict__ attn) {
    int b = blockIdx.x, tid = threadIdx.x;
    int lane = tid & 63, wid = tid >> 6;
    __shared__ float s_w[NCHUNK];
    __shared__ float sM, sinvL;

    if (wid == 0) {
        float mj = (lane < NCHUNK) ? m_ws[b * NCHUNK + lane] : -3.4e38f;
        float lj = (lane < NCHUNK) ? l_ws[b * NCHUNK + lane] : 0.f;
        float M = mj;
        #pragma unroll
        for (int s = 32; s; s >>= 1) M = fmaxf(M, __shfl_xor(M, s));
        float w = (lj > 0.f) ? __expf(mj - M) : 0.f;
        float L = lj * w;
        #pragma unroll
        for (int s = 32; s; s >>= 1) L += __shfl_xor(L, s);
        if (lane < NCHUNK) s_w[lane] = w;
        if (lane == 0) { sM = M; sinvL = 1.f / L; }
    }
    __syncthreads();
    float M = sM, invL = sinvL;

    {
        int e2 = tid * 2;
        float ax = 0.f, ay = 0.f;
        #pragma unroll
        for (int j = 0; j < NCHUNK; ++j) {
            float w = s_w[j];
            if (w != 0.f) {
                float2 v = *reinterpret_cast<const float2*>(c_ws + ((size_t)(b * NCHUNK + j)) * Edim + e2);
                ax += w * v.x; ay += w * v.y;
            }
        }
        *reinterpret_cast<float2*>(ctx + (size_t)b * Edim + e2) = make_float2(ax * invL, ay * invL);
    }

    int len = lengths[b];
    #pragma unroll
    for (int i = 0; i < Tdim / 256; ++i) {
        int t = tid + i * 256;
        float s = attn[(size_t)b * Tdim + t];
        attn[(size_t)b * Tdim + t] = (t < len) ? __expf(s - M) * invL : 0.f;
    }
}

extern "C" void kernel_launch(void* const* d_in, const int* in_sizes, int n_in,
                              void* d_out, int out_size, void* d_ws, size_t ws_size,
                              hipStream_t stream) {
    const float* queries = (const float*)d_in[0];
    const float* prev    = (const float*)d_in[1];
    const float* enc     = (const float*)d_in[2];
    const float* conv_w  = (const float*)d_in[3];
    const float* conv_b  = (const float*)d_in[4];
    const float* Wq      = (const float*)d_in[5];
    const float* Wk      = (const float*)d_in[6];
    const float* v_w     = (const float*)d_in[7];
    const float* v_b     = (const float*)d_in[8];
    const float* bparam  = (const float*)d_in[9];
    const int*   lengths = (const int*)d_in[10];

    float* out  = (float*)d_out;
    float* ctx  = out;                       // B*E = 32768
    float* attn = out + Bsz * Edim;          // B*T = 131072

    char* ws = (char*)d_ws;
    unsigned short* wkbf = (unsigned short*)ws;                 // 128 KB (pre-swizzled)
    float* qb   = (float*)(ws + 131072);                        // 32 KB
    float* m_ws = (float*)(ws + 163840);                        // 2 KB
    float* l_ws = (float*)(ws + 172032);                        // 2 KB
    float* c_ws = (float*)(ws + 196608);                        // 1 MB

    k_prep<<<272, 256, 0, stream>>>(queries, Wq, bparam, conv_b, Wk, wkbf, qb);
    k_score_ctx<<<dim3(Bsz, NCHUNK), 512, 0, stream>>>(enc, prev, wkbf, qb, conv_w, v_w, v_b,
                                                       lengths, attn, m_ws, l_ws, c_ws);
    k_combine<<<Bsz, 256, 0, stream>>>(m_ws, l_ws, c_ws, lengths, ctx, attn);
}